// Round 1
// baseline (4812.304 us; speedup 1.0000x reference)
//
#include <hip/hip_runtime.h>
#include <cmath>

#define B_SZ    4
#define N_SEQ   1536
#define D_MODEL 1536
#define H_N     8
#define DK      64
#define DV      192
#define HDK     512    // H_N*DK
#define HDV     1536   // H_N*DV
#define NRPF    192
#define NB      32
#define NREL    3071   // 2*N_SEQ-1
#define QB      8

// ---------------- positional embedding (3071 x 192) -----------------
__global__ void pos_embed_kernel(float* __restrict__ pos) {
    int r = blockIdx.x;          // 0..3070
    int j = threadIdx.x;         // 0..95
    float dist = (float)(r - (N_SEQ - 1));
    float absd = fabsf(dist);
    __shared__ float gprobs[NB];
    int cls = j >> 5;            // 0: exp, 1: central mask, 2: gamma
    int jj  = j & 31;
    float val = 0.0f;
    if (cls == 0) {
        const float max_range = 10.584962500721156f; // log2(1536)
        float hl = exp2f(3.0f + (float)jj * (max_range - 3.0f) / 31.0f);
        val = expf(-0.6931471805599453f / hl * absd);
    } else if (cls == 1) {
        float cw = exp2f((float)(jj + 1)) - 1.0f;
        val = (cw > absd) ? 1.0f : 0.0f;
    } else {
        float mean = 48.0f + (float)jj * (1536.0f - 48.0f) / 31.0f;
        float conc = (mean / 24.0f) * (mean / 24.0f);
        float rate = mean / 576.0f;
        float lu = (conc - 1.0f) * logf(absd) - rate * absd;   // absd=0 -> -inf -> exp=0
        float ln = lgammaf(conc) - conc * logf(rate);
        float prob = expf(lu - ln) + 1e-8f;
        gprobs[jj] = prob;
        val = prob;
    }
    __syncthreads();
    if (cls == 2) {
        float mx = gprobs[0];
        #pragma unroll
        for (int t = 1; t < NB; ++t) mx = fmaxf(mx, gprobs[t]);
        val = val / mx;
    }
    float sgn = (dist > 0.f) ? 1.f : ((dist < 0.f) ? -1.f : 0.f);
    pos[(size_t)r * NRPF + j]      = val;
    pos[(size_t)r * NRPF + 96 + j] = sgn * val;
}

// ---------------- tiled f32 GEMM: C = alpha*(A@B) (+bias) -----------------
// A: MxK row-major, B: KxN row-major. Requires K%16==0, N%64==0 (true for all calls).
#define GBM 64
#define GBN 64
#define GBK 16
__global__ __launch_bounds__(256) void gemm_f32(
    const float* __restrict__ A, const float* __restrict__ Bm,
    float* __restrict__ C, int M, int N, int K,
    float alpha, const float* __restrict__ bias) {
    __shared__ float As[GBM][GBK + 1];
    __shared__ float Bs[GBK][GBN];
    int tid = threadIdx.x;
    int tm = tid >> 4, tn = tid & 15;
    int row0 = blockIdx.y * GBM, col0 = blockIdx.x * GBN;
    float acc[4][4] = {};
    int ar = tid >> 2, ac = (tid & 3) * 4;    // A tile: 64x16, one float4/thread
    int br = tid >> 4, bc = (tid & 15) * 4;   // B tile: 16x64, one float4/thread
    for (int k0 = 0; k0 < K; k0 += GBK) {
        int gar = row0 + ar;
        float4 a4;
        if (gar < M) a4 = *(const float4*)(A + (size_t)gar * K + k0 + ac);
        else         a4 = make_float4(0.f, 0.f, 0.f, 0.f);
        As[ar][ac + 0] = a4.x; As[ar][ac + 1] = a4.y;
        As[ar][ac + 2] = a4.z; As[ar][ac + 3] = a4.w;
        float4 b4 = *(const float4*)(Bm + (size_t)(k0 + br) * N + col0 + bc);
        *(float4*)(&Bs[br][bc]) = b4;
        __syncthreads();
        #pragma unroll
        for (int kk = 0; kk < GBK; ++kk) {
            float av[4];
            #pragma unroll
            for (int i = 0; i < 4; ++i) av[i] = As[tm * 4 + i][kk];
            float4 bq = *(const float4*)(&Bs[kk][tn * 4]);
            float bv[4] = {bq.x, bq.y, bq.z, bq.w};
            #pragma unroll
            for (int i = 0; i < 4; ++i)
                #pragma unroll
                for (int jx = 0; jx < 4; ++jx)
                    acc[i][jx] += av[i] * bv[jx];
        }
        __syncthreads();
    }
    #pragma unroll
    for (int i = 0; i < 4; ++i) {
        int gr = row0 + tm * 4 + i;
        if (gr >= M) continue;
        #pragma unroll
        for (int jx = 0; jx < 4; ++jx) {
            int gc = col0 + tn * 4 + jx;
            float vv = acc[i][jx] * alpha;
            if (bias) vv += bias[gc];
            C[(size_t)gr * N + gc] = vv;
        }
    }
}

// ---------------- fused attention: one block per (b, h, 8 queries) -----------------
__global__ __launch_bounds__(256) void attn_kernel(
    const float* __restrict__ q, const float* __restrict__ k,
    const float* __restrict__ v, const float* __restrict__ relk,
    const float* __restrict__ cb, const float* __restrict__ pb,
    float* __restrict__ att) {
    __shared__ float s[N_SEQ][QB];            // 48 KiB logits/probs
    __shared__ float qc[QB][DK], qp[QB][DK];  // 4 KiB
    __shared__ float wred[4][QB];
    __shared__ float mq[QB], dq[QB];
    int i0  = blockIdx.x * QB;
    int h   = blockIdx.y;
    int b   = blockIdx.z;
    int tid = threadIdx.x;
    // stage q rows (+ biases); q is already scaled by 0.125 in the GEMM
    for (int idx = tid; idx < QB * DK; idx += 256) {
        int qi = idx >> 6, d = idx & 63;
        float qv = q[((size_t)(b * N_SEQ + i0 + qi)) * HDK + h * DK + d];
        qc[qi][d] = qv + cb[h * DK + d];
        qp[qi][d] = qv + pb[h * DK + d];
    }
    __syncthreads();
    // content logits: s[j][qi] = qc_qi . k_j
    for (int j = tid; j < N_SEQ; j += 256) {
        const float* krow = k + ((size_t)(b * N_SEQ + j)) * HDK + h * DK;
        float acc[QB] = {};
        for (int d = 0; d < DK; d += 4) {
            float4 k4 = *(const float4*)(krow + d);
            #pragma unroll
            for (int qi = 0; qi < QB; ++qi) {
                float4 q4 = *(const float4*)(&qc[qi][d]);
                acc[qi] += q4.x * k4.x + q4.y * k4.y + q4.z * k4.z + q4.w * k4.w;
            }
        }
        #pragma unroll
        for (int qi = 0; qi < QB; ++qi) s[j][qi] = acc[qi];
    }
    __syncthreads();
    // rel logits over diagonals: for t = j - qi, rel row r = N-1 + t - i0 is shared by all qi
    for (int tt = tid; tt < N_SEQ + QB - 1; tt += 256) {
        int rrow_i = N_SEQ - QB + tt - i0;    // = N-1 + (tt-(QB-1)) - i0, in [0, 2N-2]
        const float* rrow = relk + (size_t)rrow_i * HDK + h * DK;
        float acc[QB] = {};
        for (int d = 0; d < DK; d += 4) {
            float4 r4 = *(const float4*)(rrow + d);
            #pragma unroll
            for (int qi = 0; qi < QB; ++qi) {
                float4 q4 = *(const float4*)(&qp[qi][d]);
                acc[qi] += q4.x * r4.x + q4.y * r4.y + q4.z * r4.z + q4.w * r4.w;
            }
        }
        int t = tt - (QB - 1);
        #pragma unroll
        for (int qi = 0; qi < QB; ++qi) {
            int j = t + qi;
            if (j >= 0 && j < N_SEQ) s[j][qi] += acc[qi];
        }
    }
    __syncthreads();
    // softmax: max
    float lm[QB];
    #pragma unroll
    for (int qi = 0; qi < QB; ++qi) lm[qi] = -1e30f;
    for (int j = tid; j < N_SEQ; j += 256) {
        #pragma unroll
        for (int qi = 0; qi < QB; ++qi) lm[qi] = fmaxf(lm[qi], s[j][qi]);
    }
    #pragma unroll
    for (int qi = 0; qi < QB; ++qi)
        for (int off = 32; off > 0; off >>= 1)
            lm[qi] = fmaxf(lm[qi], __shfl_xor(lm[qi], off, 64));
    int lane = tid & 63, wave = tid >> 6;
    if (lane == 0) {
        #pragma unroll
        for (int qi = 0; qi < QB; ++qi) wred[wave][qi] = lm[qi];
    }
    __syncthreads();
    if (tid < QB)
        mq[tid] = fmaxf(fmaxf(wred[0][tid], wred[1][tid]),
                        fmaxf(wred[2][tid], wred[3][tid]));
    __syncthreads();
    float mreg[QB];
    #pragma unroll
    for (int qi = 0; qi < QB; ++qi) mreg[qi] = mq[qi];
    // exp + sum
    float lsum[QB] = {};
    for (int j = tid; j < N_SEQ; j += 256) {
        #pragma unroll
        for (int qi = 0; qi < QB; ++qi) {
            float p = expf(s[j][qi] - mreg[qi]);
            s[j][qi] = p;
            lsum[qi] += p;
        }
    }
    #pragma unroll
    for (int qi = 0; qi < QB; ++qi)
        for (int off = 32; off > 0; off >>= 1)
            lsum[qi] += __shfl_xor(lsum[qi], off, 64);
    if (lane == 0) {
        #pragma unroll
        for (int qi = 0; qi < QB; ++qi) wred[wave][qi] = lsum[qi];
    }
    __syncthreads();
    if (tid < QB)
        dq[tid] = wred[0][tid] + wred[1][tid] + wred[2][tid] + wred[3][tid];
    __syncthreads();
    // PV: 192 lanes own output dims
    if (tid < DV) {
        float acc[QB] = {};
        const float* vcol = v + ((size_t)b * N_SEQ) * HDV + h * DV + tid;
        for (int j = 0; j < N_SEQ; ++j) {
            float vv = vcol[(size_t)j * HDV];
            float4 a = *(const float4*)(&s[j][0]);
            float4 c = *(const float4*)(&s[j][4]);
            acc[0] += a.x * vv; acc[1] += a.y * vv;
            acc[2] += a.z * vv; acc[3] += a.w * vv;
            acc[4] += c.x * vv; acc[5] += c.y * vv;
            acc[6] += c.z * vv; acc[7] += c.w * vv;
        }
        #pragma unroll
        for (int qi = 0; qi < QB; ++qi)
            att[((size_t)(b * N_SEQ + i0 + qi)) * HDV + h * DV + tid] = acc[qi] / dq[qi];
    }
}

extern "C" void kernel_launch(void* const* d_in, const int* in_sizes, int n_in,
                              void* d_out, int out_size, void* d_ws, size_t ws_size,
                              hipStream_t stream) {
    const float* x    = (const float*)d_in[0];
    const float* Wq   = (const float*)d_in[1];
    const float* Wk   = (const float*)d_in[2];
    const float* Wv   = (const float*)d_in[3];
    const float* Wrel = (const float*)d_in[4];
    const float* cb   = (const float*)d_in[5];
    const float* pb   = (const float*)d_in[6];
    const float* Wout = (const float*)d_in[7];
    const float* bout = (const float*)d_in[8];
    float* out = (float*)d_out;

    float* ws   = (float*)d_ws;
    float* pos  = ws;                                  // 3071*192
    float* relk = pos  + (size_t)NREL * NRPF;          // 3071*512
    float* qbuf = relk + (size_t)NREL * HDK;           // 6144*512
    float* kbuf = qbuf + (size_t)B_SZ * N_SEQ * HDK;   // 6144*512
    float* vbuf = kbuf + (size_t)B_SZ * N_SEQ * HDK;   // 6144*1536
    float* att  = vbuf + (size_t)B_SZ * N_SEQ * HDV;   // 6144*1536

    dim3 blk(256);
    pos_embed_kernel<<<NREL, 96, 0, stream>>>(pos);
    const int M = B_SZ * N_SEQ;
    gemm_f32<<<dim3(HDK / 64, M / 64), blk, 0, stream>>>(
        x, Wq, qbuf, M, HDK, D_MODEL, 0.125f, nullptr);
    gemm_f32<<<dim3(HDK / 64, M / 64), blk, 0, stream>>>(
        x, Wk, kbuf, M, HDK, D_MODEL, 1.0f, nullptr);
    gemm_f32<<<dim3(HDV / 64, M / 64), blk, 0, stream>>>(
        x, Wv, vbuf, M, HDV, D_MODEL, 1.0f, nullptr);
    gemm_f32<<<dim3(HDK / 64, (NREL + 63) / 64), blk, 0, stream>>>(
        pos, Wrel, relk, NREL, HDK, NRPF, 1.0f, nullptr);
    attn_kernel<<<dim3(N_SEQ / QB, H_N, B_SZ), blk, 0, stream>>>(
        qbuf, kbuf, vbuf, relk, cb, pb, att);
    gemm_f32<<<dim3(D_MODEL / 64, M / 64), blk, 0, stream>>>(
        att, Wout, out, M, D_MODEL, HDV, 1.0f, bout);
}

// Round 2
// 1536.779 us; speedup vs baseline: 3.1314x; 3.1314x over previous
//
#include <hip/hip_runtime.h>
#include <cmath>

#define B_SZ    4
#define N_SEQ   1536
#define D_MODEL 1536
#define H_N     8
#define DK      64
#define DV      192
#define HDK     512
#define HDV     1536
#define NRPF    192
#define NB      32
#define NREL    3071

typedef unsigned short u16;
typedef __attribute__((ext_vector_type(8))) short short8;
typedef __attribute__((ext_vector_type(4))) float f32x4;

#define MFMA_B16(a, b, c) __builtin_amdgcn_mfma_f32_16x16x32_bf16(a, b, c, 0, 0, 0)

__device__ __forceinline__ float bf2f(u16 u) {
    union { unsigned u; float f; } x; x.u = ((unsigned)u) << 16; return x.f;
}
__device__ __forceinline__ u16 f2bf(float f) {
    union { float f; unsigned u; } x; x.f = f;
    unsigned r = x.u + 0x7FFFu + ((x.u >> 16) & 1u);
    return (u16)(r >> 16);
}

// ---------------- positional embedding (3071 x 192) -----------------
__global__ void pos_embed_kernel(float* __restrict__ pos) {
    int r = blockIdx.x;
    int j = threadIdx.x;          // 0..95
    float dist = (float)(r - (N_SEQ - 1));
    float absd = fabsf(dist);
    __shared__ float gprobs[NB];
    int cls = j >> 5;
    int jj  = j & 31;
    float val = 0.0f;
    if (cls == 0) {
        const float max_range = 10.584962500721156f; // log2(1536)
        float hl = exp2f(3.0f + (float)jj * (max_range - 3.0f) / 31.0f);
        val = expf(-0.6931471805599453f / hl * absd);
    } else if (cls == 1) {
        float cw = exp2f((float)(jj + 1)) - 1.0f;
        val = (cw > absd) ? 1.0f : 0.0f;
    } else {
        float mean = 48.0f + (float)jj * (1536.0f - 48.0f) / 31.0f;
        float conc = (mean / 24.0f) * (mean / 24.0f);
        float rate = mean / 576.0f;
        float lu = (conc - 1.0f) * logf(absd) - rate * absd;
        float ln = lgammaf(conc) - conc * logf(rate);
        float prob = expf(lu - ln) + 1e-8f;
        gprobs[jj] = prob;
        val = prob;
    }
    __syncthreads();
    if (cls == 2) {
        float mx = gprobs[0];
        #pragma unroll
        for (int t = 1; t < NB; ++t) mx = fmaxf(mx, gprobs[t]);
        val = val / mx;
    }
    float sgn = (dist > 0.f) ? 1.f : ((dist < 0.f) ? -1.f : 0.f);
    pos[(size_t)r * NRPF + j]      = val;
    pos[(size_t)r * NRPF + 96 + j] = sgn * val;
}

// ---------------- tiled f32 GEMM, optional bf16 output -----------------
#define GBM 64
#define GBN 64
#define GBK 16
__global__ __launch_bounds__(256) void gemm_f32(
    const float* __restrict__ A, const float* __restrict__ Bm,
    float* __restrict__ C, u16* __restrict__ Cb16, int M, int N, int K,
    float alpha, const float* __restrict__ bias) {
    __shared__ float As[GBM][GBK + 1];
    __shared__ float Bs[GBK][GBN];
    int tid = threadIdx.x;
    int tm = tid >> 4, tn = tid & 15;
    int row0 = blockIdx.y * GBM, col0 = blockIdx.x * GBN;
    float acc[4][4] = {};
    int ar = tid >> 2, ac = (tid & 3) * 4;
    int br = tid >> 4, bc = (tid & 15) * 4;
    for (int k0 = 0; k0 < K; k0 += GBK) {
        int gar = row0 + ar;
        float4 a4;
        if (gar < M) a4 = *(const float4*)(A + (size_t)gar * K + k0 + ac);
        else         a4 = make_float4(0.f, 0.f, 0.f, 0.f);
        As[ar][ac + 0] = a4.x; As[ar][ac + 1] = a4.y;
        As[ar][ac + 2] = a4.z; As[ar][ac + 3] = a4.w;
        float4 b4 = *(const float4*)(Bm + (size_t)(k0 + br) * N + col0 + bc);
        *(float4*)(&Bs[br][bc]) = b4;
        __syncthreads();
        #pragma unroll
        for (int kk = 0; kk < GBK; ++kk) {
            float av[4];
            #pragma unroll
            for (int i = 0; i < 4; ++i) av[i] = As[tm * 4 + i][kk];
            float4 bq = *(const float4*)(&Bs[kk][tn * 4]);
            float bv[4] = {bq.x, bq.y, bq.z, bq.w};
            #pragma unroll
            for (int i = 0; i < 4; ++i)
                #pragma unroll
                for (int jx = 0; jx < 4; ++jx)
                    acc[i][jx] += av[i] * bv[jx];
        }
        __syncthreads();
    }
    #pragma unroll
    for (int i = 0; i < 4; ++i) {
        int gr = row0 + tm * 4 + i;
        if (gr >= M) continue;
        #pragma unroll
        for (int jx = 0; jx < 4; ++jx) {
            int gc = col0 + tn * 4 + jx;
            float vv = acc[i][jx] * alpha;
            if (bias) vv += bias[gc];
            if (Cb16) Cb16[(size_t)gr * N + gc] = f2bf(vv);
            else      C[(size_t)gr * N + gc] = vv;
        }
    }
}

// ---------------- V transpose: v_bf16[b*N+n][h*192+c] -> vt[(b*8+h)*192+c][n] ----------
__global__ __launch_bounds__(256) void transpose_v(const u16* __restrict__ vb,
                                                   u16* __restrict__ vt) {
    __shared__ u16 tile[64][72];
    int nt = blockIdx.x, ct = blockIdx.y, bh = blockIdx.z;
    int b = bh >> 3, h = bh & 7;
    int tid = threadIdx.x;
    for (int t = tid; t < 512; t += 256) {
        int r = t >> 3, ch = t & 7;
        short8 v = *(const short8*)(vb + ((size_t)(b * N_SEQ + nt * 64 + r)) * HDV
                                       + h * DV + ct * 64 + ch * 8);
        #pragma unroll
        for (int e = 0; e < 8; ++e) tile[ch * 8 + e][r] = (u16)v[e];
    }
    __syncthreads();
    for (int t = tid; t < 512; t += 256) {
        int c = t >> 3, ch = t & 7;
        short8 v;
        #pragma unroll
        for (int e = 0; e < 8; ++e) v[e] = (short)tile[c][ch * 8 + e];
        *(short8*)(vt + ((size_t)((b * 8 + h) * DV + ct * 64 + c)) * N_SEQ
                      + nt * 64 + ch * 8) = v;
    }
}

// ---------------- MFMA flash attention with relative-position logits ----------------
// block = (i-tile of 64 queries, h, b); 4 waves x 16 rows. LDS 75,264 B -> 2 blocks/CU.
__global__ __launch_bounds__(256, 2) void attn_mfma(
    const u16* __restrict__ qb, const u16* __restrict__ kb,
    const u16* __restrict__ vtb, const u16* __restrict__ relkb,
    const float* __restrict__ cbias, const float* __restrict__ pbias,
    float* __restrict__ att) {
    __shared__ u16 sQc[64 * 64] __attribute__((aligned(16)));
    __shared__ u16 sQp[64 * 64] __attribute__((aligned(16)));
    __shared__ u16 sKP[64 * 64] __attribute__((aligned(16)));   // K tile, reused for P
    __shared__ u16 sRs[128 * 64] __attribute__((aligned(16)));  // rel window (127 + 1 zero)
    __shared__ float sG[64 * 134] __attribute__((aligned(16))); // rel-logit scratch

    const int tid  = threadIdx.x;
    const int lane = tid & 63;
    const int w    = tid >> 6;
    const int i0   = blockIdx.x * 64;
    const int h    = blockIdx.y;
    const int b    = blockIdx.z;

    // stage Q tile (+ biases), bf16, swizzled chunks
    for (int t = tid; t < 512; t += 256) {
        const int row = t >> 3, ch = t & 7;
        short8 v = *(const short8*)(qb + ((size_t)(b * N_SEQ + i0 + row)) * HDK
                                       + h * DK + ch * 8);
        short8 c8, p8;
        #pragma unroll
        for (int e = 0; e < 8; ++e) {
            float f = bf2f((u16)v[e]);
            c8[e] = (short)f2bf(f + cbias[h * DK + ch * 8 + e]);
            p8[e] = (short)f2bf(f + pbias[h * DK + ch * 8 + e]);
        }
        const int dst = row * 64 + ((ch ^ (row & 7)) * 8);
        *(short8*)&sQc[dst] = c8;
        *(short8*)&sQp[dst] = p8;
    }
    __syncthreads();

    // Q fragments are j-invariant: load once
    const int arow = w * 16 + (lane & 15);
    short8 aqc[2], aqp[2];
    #pragma unroll
    for (int s = 0; s < 2; ++s) {
        const int off = arow * 64 + (((s * 4 + (lane >> 4)) ^ (arow & 7)) * 8);
        aqc[s] = *(const short8*)&sQc[off];
        aqp[s] = *(const short8*)&sQp[off];
    }

    f32x4 O[12];
    #pragma unroll
    for (int i = 0; i < 12; ++i) O[i] = (f32x4){0.f, 0.f, 0.f, 0.f};
    float M[4] = {-3e38f, -3e38f, -3e38f, -3e38f};
    float L[4] = {0.f, 0.f, 0.f, 0.f};
    const int growb = w * 16 + ((lane >> 4) << 2);

    for (int jt = 0; jt < 24; ++jt) {
        const int j0 = jt * 64;
        // stage K tile
        for (int t = tid; t < 512; t += 256) {
            const int row = t >> 3, ch = t & 7;
            short8 v = *(const short8*)(kb + ((size_t)(b * N_SEQ + j0 + row)) * HDK
                                           + h * DK + ch * 8);
            *(short8*)&sKP[row * 64 + ((ch ^ (row & 7)) * 8)] = v;
        }
        // stage rel window: rows rbase..rbase+126 (always in [0, 3070]); row 127 zero
        const int rbase = (N_SEQ - 64) + j0 - i0;   // 1472 + j0 - i0
        for (int t = tid; t < 1024; t += 256) {
            const int row = t >> 3, ch = t & 7;
            short8 v = {0, 0, 0, 0, 0, 0, 0, 0};
            if (row < 127)
                v = *(const short8*)(relkb + ((size_t)(rbase + row)) * HDK
                                           + h * DK + ch * 8);
            *(short8*)&sRs[row * 64 + ((ch ^ (row & 7)) * 8)] = v;
        }
        __syncthreads();

        // QK^T: S strip 16x64 ; rel window GEMM: G strip 16x128
        f32x4 S[4], G[8];
        #pragma unroll
        for (int f = 0; f < 4; ++f) S[f] = (f32x4){0.f, 0.f, 0.f, 0.f};
        #pragma unroll
        for (int f = 0; f < 8; ++f) G[f] = (f32x4){0.f, 0.f, 0.f, 0.f};
        #pragma unroll
        for (int s = 0; s < 2; ++s) {
            #pragma unroll
            for (int f = 0; f < 4; ++f) {
                const int br = f * 16 + (lane & 15);
                short8 bb = *(const short8*)&sKP[br * 64 + (((s * 4 + (lane >> 4)) ^ (br & 7)) * 8)];
                S[f] = MFMA_B16(aqc[s], bb, S[f]);
            }
            #pragma unroll
            for (int f = 0; f < 8; ++f) {
                const int br = f * 16 + (lane & 15);
                short8 bb = *(const short8*)&sRs[br * 64 + (((s * 4 + (lane >> 4)) ^ (br & 7)) * 8)];
                G[f] = MFMA_B16(aqp[s], bb, G[f]);
            }
        }
        // spill G to LDS (stride 134: shear-read `+jj-ii` stays conflict-free)
        #pragma unroll
        for (int f = 0; f < 8; ++f)
            #pragma unroll
            for (int r = 0; r < 4; ++r)
                sG[(growb + r) * 134 + f * 16 + (lane & 15)] = G[f][r];
        __syncthreads();   // also: all waves done reading sKP -> safe to write P later

        // sheared gather of rel logits + online softmax (rows live in 16-lane groups)
        #pragma unroll
        for (int r = 0; r < 4; ++r) {
            const int ii = growb + r;
            const int gb = ii * 133 + 63;        // ii*134 + (jj - ii + 63) base
            float mr = -3e38f;
            #pragma unroll
            for (int f = 0; f < 4; ++f) {
                const float val = S[f][r] + sG[gb + f * 16 + (lane & 15)];
                S[f][r] = val;
                mr = fmaxf(mr, val);
            }
            mr = fmaxf(mr, __shfl_xor(mr, 1, 64));
            mr = fmaxf(mr, __shfl_xor(mr, 2, 64));
            mr = fmaxf(mr, __shfl_xor(mr, 4, 64));
            mr = fmaxf(mr, __shfl_xor(mr, 8, 64));
            const float newM = fmaxf(M[r], mr);
            const float sc = __expf(M[r] - newM);
            M[r] = newM;
            float rs = 0.f;
            #pragma unroll
            for (int f = 0; f < 4; ++f) {
                const float p = __expf(S[f][r] - newM);
                S[f][r] = p;
                rs += p;
            }
            rs += __shfl_xor(rs, 1, 64);
            rs += __shfl_xor(rs, 2, 64);
            rs += __shfl_xor(rs, 4, 64);
            rs += __shfl_xor(rs, 8, 64);
            L[r] = L[r] * sc + rs;
            #pragma unroll
            for (int cf = 0; cf < 12; ++cf) O[cf][r] *= sc;
        }
        // P -> bf16 into sKP (K tile dead)
        #pragma unroll
        for (int f = 0; f < 4; ++f) {
            const int jj = f * 16 + (lane & 15);
            #pragma unroll
            for (int r = 0; r < 4; ++r) {
                const int ii = growb + r;
                sKP[ii * 64 + (((jj >> 3) ^ (ii & 7)) * 8) + (jj & 7)] = f2bf(S[f][r]);
            }
        }
        __syncthreads();
        // PV: O += P @ V_tile ; B-fragments from pre-transposed vt (16B contiguous)
        #pragma unroll
        for (int s = 0; s < 2; ++s) {
            short8 a = *(const short8*)&sKP[arow * 64 + (((s * 4 + (lane >> 4)) ^ (arow & 7)) * 8)];
            const u16* vp = vtb + ((size_t)((b * 8 + h) * DV + (lane & 15))) * N_SEQ
                                + j0 + s * 32 + 8 * (lane >> 4);
            #pragma unroll
            for (int cf = 0; cf < 12; ++cf) {
                short8 bb = *(const short8*)(vp + (size_t)cf * 16 * N_SEQ);
                O[cf] = MFMA_B16(a, bb, O[cf]);
            }
        }
        __syncthreads();
    }
    // epilogue: divide by softmax denominator, write f32
    #pragma unroll
    for (int cf = 0; cf < 12; ++cf) {
        #pragma unroll
        for (int r = 0; r < 4; ++r) {
            const int ii = growb + r;
            att[((size_t)(b * N_SEQ + i0 + ii)) * HDV + h * DV + cf * 16 + (lane & 15)] =
                O[cf][r] / L[r];
        }
    }
}

extern "C" void kernel_launch(void* const* d_in, const int* in_sizes, int n_in,
                              void* d_out, int out_size, void* d_ws, size_t ws_size,
                              hipStream_t stream) {
    const float* x    = (const float*)d_in[0];
    const float* Wq   = (const float*)d_in[1];
    const float* Wk   = (const float*)d_in[2];
    const float* Wv   = (const float*)d_in[3];
    const float* Wrel = (const float*)d_in[4];
    const float* cb   = (const float*)d_in[5];
    const float* pb   = (const float*)d_in[6];
    const float* Wout = (const float*)d_in[7];
    const float* bout = (const float*)d_in[8];
    float* out = (float*)d_out;

    const int M = B_SZ * N_SEQ;                       // 6144
    float* ws   = (float*)d_ws;
    float* pos  = ws;                                 // 3071*192 f32
    float* att  = pos + (size_t)NREL * NRPF;          // 6144*1536 f32
    u16* qb     = (u16*)(att + (size_t)M * HDV);      // 6144*512 bf16
    u16* kb     = qb + (size_t)M * HDK;               // 6144*512 bf16
    u16* relkb  = kb + (size_t)M * HDK;               // 3071*512 bf16
    u16* vb     = relkb + (size_t)NREL * HDK;         // 6144*1536 bf16
    u16* vtb    = vb + (size_t)M * HDV;               // 32*192*1536 bf16

    dim3 blk(256);
    pos_embed_kernel<<<NREL, 96, 0, stream>>>(pos);
    gemm_f32<<<dim3(HDK / 64, M / 64), blk, 0, stream>>>(
        x, Wq, nullptr, qb, M, HDK, D_MODEL, 0.125f, nullptr);
    gemm_f32<<<dim3(HDK / 64, M / 64), blk, 0, stream>>>(
        x, Wk, nullptr, kb, M, HDK, D_MODEL, 1.0f, nullptr);
    gemm_f32<<<dim3(HDV / 64, M / 64), blk, 0, stream>>>(
        x, Wv, nullptr, vb, M, HDV, D_MODEL, 1.0f, nullptr);
    gemm_f32<<<dim3(HDK / 64, (NREL + 63) / 64), blk, 0, stream>>>(
        pos, Wrel, nullptr, relkb, NREL, HDK, NRPF, 1.0f, nullptr);
    transpose_v<<<dim3(N_SEQ / 64, DV / 64, B_SZ * H_N), blk, 0, stream>>>(vb, vtb);
    attn_mfma<<<dim3(N_SEQ / 64, H_N, B_SZ), blk, 0, stream>>>(
        qb, kb, vtb, relkb, cb, pb, att);
    gemm_f32<<<dim3(D_MODEL / 64, M / 64), blk, 0, stream>>>(
        att, Wout, out, nullptr, M, D_MODEL, HDV, 1.0f, bout);
}

// Round 3
// 628.873 us; speedup vs baseline: 7.6523x; 2.4437x over previous
//
#include <hip/hip_runtime.h>
#include <cmath>

#define B_SZ    4
#define N_SEQ   1536
#define D_MODEL 1536
#define H_N     8
#define DK      64
#define DV      192
#define HDK     512
#define HDV     1536
#define NRPF    192
#define NB      32
#define NREL    3071
#define QKS     1024   // row stride of fused q|k buffer

typedef unsigned short u16;
typedef __attribute__((ext_vector_type(8))) short short8;
typedef __attribute__((ext_vector_type(4))) float f32x4;

#define MFMA_B16(a, b, c) __builtin_amdgcn_mfma_f32_16x16x32_bf16(a, b, c, 0, 0, 0)

__device__ __forceinline__ float bf2f(u16 u) {
    union { unsigned u; float f; } x; x.u = ((unsigned)u) << 16; return x.f;
}
__device__ __forceinline__ u16 f2bf(float f) {
    union { float f; unsigned u; } x; x.f = f;
    unsigned r = x.u + 0x7FFFu + ((x.u >> 16) & 1u);
    return (u16)(r >> 16);
}
__device__ __forceinline__ void gload16(const u16* g, u16* l) {
    __builtin_amdgcn_global_load_lds(
        (const __attribute__((address_space(1))) unsigned int*)(const void*)g,
        (__attribute__((address_space(3))) unsigned int*)(void*)l, 16, 0, 0);
}

// ---------------- positional embedding -> bf16 (3072 x 192, row 3071 = 0) ------------
__global__ void pos_embed_kernel(u16* __restrict__ pos) {
    int r = blockIdx.x;           // 0..3071
    int j = threadIdx.x;          // 0..95
    if (r >= NREL) {              // zero pad row (whole block -> no barrier issue)
        pos[(size_t)r * NRPF + j] = 0;
        pos[(size_t)r * NRPF + 96 + j] = 0;
        return;
    }
    float dist = (float)(r - (N_SEQ - 1));
    float absd = fabsf(dist);
    __shared__ float gprobs[NB];
    int cls = j >> 5;
    int jj  = j & 31;
    float val = 0.0f;
    if (cls == 0) {
        const float max_range = 10.584962500721156f; // log2(1536)
        float hl = exp2f(3.0f + (float)jj * (max_range - 3.0f) / 31.0f);
        val = expf(-0.6931471805599453f / hl * absd);
    } else if (cls == 1) {
        float cw = exp2f((float)(jj + 1)) - 1.0f;
        val = (cw > absd) ? 1.0f : 0.0f;
    } else {
        float mean = 48.0f + (float)jj * (1536.0f - 48.0f) / 31.0f;
        float conc = (mean / 24.0f) * (mean / 24.0f);
        float rate = mean / 576.0f;
        float lu = (conc - 1.0f) * logf(absd) - rate * absd;
        float ln = lgammaf(conc) - conc * logf(rate);
        float prob = expf(lu - ln) + 1e-8f;
        gprobs[jj] = prob;
        val = prob;
    }
    __syncthreads();
    if (cls == 2) {
        float mx = gprobs[0];
        #pragma unroll
        for (int t = 1; t < NB; ++t) mx = fmaxf(mx, gprobs[t]);
        val = val / mx;
    }
    float sgn = (dist > 0.f) ? 1.f : ((dist < 0.f) ? -1.f : 0.f);
    pos[(size_t)r * NRPF + j]      = f2bf(val);
    pos[(size_t)r * NRPF + 96 + j] = f2bf(sgn * val);
}

// ---------------- f32 -> bf16 convert (n divisible by 8) -----------------
__global__ __launch_bounds__(256) void cvt_bf16(const float* __restrict__ in,
                                                u16* __restrict__ out, int n8) {
    int i = blockIdx.x * 256 + threadIdx.x;
    if (i >= n8) return;
    const float4* p = (const float4*)in;
    float4 a = p[i * 2], b = p[i * 2 + 1];
    short8 o;
    o[0] = (short)f2bf(a.x); o[1] = (short)f2bf(a.y);
    o[2] = (short)f2bf(a.z); o[3] = (short)f2bf(a.w);
    o[4] = (short)f2bf(b.x); o[5] = (short)f2bf(b.y);
    o[6] = (short)f2bf(b.z); o[7] = (short)f2bf(b.w);
    *(short8*)(out + (size_t)i * 8) = o;
}

// ---------------- weight transpose: W (KxN f32) -> Wt (NxK bf16), scaled ----------
__global__ __launch_bounds__(256) void transpose_w(const float* __restrict__ W,
                                                   u16* __restrict__ Wt,
                                                   int K, int N, float scale) {
    __shared__ float tile[32][33];
    int n0 = blockIdx.x * 32, k0 = blockIdx.y * 32;
    int tx = threadIdx.x & 31, ty = threadIdx.x >> 5;   // ty 0..7
    for (int r = ty; r < 32; r += 8) tile[r][tx] = W[(size_t)(k0 + r) * N + n0 + tx];
    __syncthreads();
    for (int r = ty; r < 32; r += 8)
        Wt[(size_t)(n0 + r) * K + k0 + tx] = f2bf(tile[tx][r] * scale);
}

// ---------------- bf16 MFMA GEMM: C = A @ Bt^T (+bias) -----------------
// A: MxK bf16 row-major; Bt: NxK bf16 row-major. M%128 (padded rows readable),
// N%128==0, K%64==0. Store guarded by Mstore.
#define BM 128
#define BN 128
#define BK 64
__global__ __launch_bounds__(256) void gemm_bf16(
    const u16* __restrict__ A, const u16* __restrict__ Bt,
    u16* __restrict__ Cb, float* __restrict__ Cf,
    const float* __restrict__ bias, int Mstore, int N, int K) {
    __shared__ u16 sA[BM * BK] __attribute__((aligned(16)));
    __shared__ u16 sB[BN * BK] __attribute__((aligned(16)));
    const int tid  = threadIdx.x;
    const int lane = tid & 63;
    const int w    = tid >> 6;
    const int wm   = w >> 1, wn = w & 1;
    const int row0 = blockIdx.y * BM, col0 = blockIdx.x * BN;

    f32x4 acc[4][4];
    #pragma unroll
    for (int i = 0; i < 4; ++i)
        #pragma unroll
        for (int j = 0; j < 4; ++j) acc[i][j] = (f32x4){0.f, 0.f, 0.f, 0.f};

    // precompute per-lane swizzled source row/chunk for the 4 staging issues
    int srow[4], soff[4];
    #pragma unroll
    for (int i = 0; i < 4; ++i) {
        const int ci = i * 256 + tid;       // 16B-chunk index, 0..1023
        const int r  = ci >> 3;             // tile row (128B rows)
        const int lc = (ci & 7) ^ (r & 7);  // inverse-swizzled logical k-chunk
        srow[i] = r;
        soff[i] = lc * 8;
    }

    for (int kt = 0; kt < K; kt += BK) {
        #pragma unroll
        for (int i = 0; i < 4; ++i) {
            gload16(A + (size_t)(row0 + srow[i]) * K + kt + soff[i],
                    sA + (i * 256 + w * 64) * 8);
            gload16(Bt + (size_t)(col0 + srow[i]) * K + kt + soff[i],
                    sB + (i * 256 + w * 64) * 8);
        }
        __syncthreads();
        short8 af[2][4], bg[2][4];
        #pragma unroll
        for (int s = 0; s < 2; ++s) {
            #pragma unroll
            for (int mi = 0; mi < 4; ++mi) {
                const int rr = wm * 64 + mi * 16 + (lane & 15);
                af[s][mi] = *(const short8*)&sA[rr * 64 + (((s * 4 + (lane >> 4)) ^ (rr & 7)) * 8)];
            }
            #pragma unroll
            for (int ni = 0; ni < 4; ++ni) {
                const int rr = wn * 64 + ni * 16 + (lane & 15);
                bg[s][ni] = *(const short8*)&sB[rr * 64 + (((s * 4 + (lane >> 4)) ^ (rr & 7)) * 8)];
            }
        }
        #pragma unroll
        for (int s = 0; s < 2; ++s)
            #pragma unroll
            for (int mi = 0; mi < 4; ++mi)
                #pragma unroll
                for (int ni = 0; ni < 4; ++ni)
                    acc[mi][ni] = MFMA_B16(af[s][mi], bg[s][ni], acc[mi][ni]);
        __syncthreads();
    }
    const int rb = (lane >> 4) * 4;
    const int cl = lane & 15;
    #pragma unroll
    for (int mi = 0; mi < 4; ++mi) {
        #pragma unroll
        for (int r = 0; r < 4; ++r) {
            const int gr = row0 + wm * 64 + mi * 16 + rb + r;
            if (gr >= Mstore) continue;
            #pragma unroll
            for (int ni = 0; ni < 4; ++ni) {
                const int gc = col0 + wn * 64 + ni * 16 + cl;
                float v = acc[mi][ni][r];
                if (bias) v += bias[gc];
                if (Cb) Cb[(size_t)gr * N + gc] = f2bf(v);
                else    Cf[(size_t)gr * N + gc] = v;
            }
        }
    }
}

// ---------------- V transpose: vb[b*N+n][h*192+c] -> vt[(b*8+h)*192+c][n] ----------
__global__ __launch_bounds__(256) void transpose_v(const u16* __restrict__ vb,
                                                   u16* __restrict__ vt) {
    __shared__ u16 tile[64][72];
    int nt = blockIdx.x, ct = blockIdx.y, bh = blockIdx.z;
    int b = bh >> 3, h = bh & 7;
    int tid = threadIdx.x;
    for (int t = tid; t < 512; t += 256) {
        int r = t >> 3, ch = t & 7;
        short8 v = *(const short8*)(vb + ((size_t)(b * N_SEQ + nt * 64 + r)) * HDV
                                       + h * DV + ct * 64 + ch * 8);
        #pragma unroll
        for (int e = 0; e < 8; ++e) tile[ch * 8 + e][r] = (u16)v[e];
    }
    __syncthreads();
    for (int t = tid; t < 512; t += 256) {
        int c = t >> 3, ch = t & 7;
        short8 v;
        #pragma unroll
        for (int e = 0; e < 8; ++e) v[e] = (short)tile[c][ch * 8 + e];
        *(short8*)(vt + ((size_t)((b * 8 + h) * DV + ct * 64 + c)) * N_SEQ
                      + nt * 64 + ch * 8) = v;
    }
}

// ---------------- MFMA flash attention with relative-position logits ----------------
__global__ __launch_bounds__(256, 2) void attn_mfma(
    const u16* __restrict__ qb, const u16* __restrict__ kb,
    const u16* __restrict__ vtb, const u16* __restrict__ relkb,
    const float* __restrict__ cbias, const float* __restrict__ pbias,
    u16* __restrict__ att) {
    __shared__ u16 sQc[64 * 64] __attribute__((aligned(16)));
    __shared__ u16 sQp[64 * 64] __attribute__((aligned(16)));
    __shared__ u16 sKP[64 * 64] __attribute__((aligned(16)));
    __shared__ u16 sRs[128 * 64] __attribute__((aligned(16)));
    __shared__ float sG[64 * 134] __attribute__((aligned(16)));

    const int tid  = threadIdx.x;
    const int lane = tid & 63;
    const int w    = tid >> 6;
    const int i0   = blockIdx.x * 64;
    const int h    = blockIdx.y;
    const int b    = blockIdx.z;

    for (int t = tid; t < 512; t += 256) {
        const int row = t >> 3, ch = t & 7;
        short8 v = *(const short8*)(qb + ((size_t)(b * N_SEQ + i0 + row)) * QKS
                                       + h * DK + ch * 8);
        short8 c8, p8;
        #pragma unroll
        for (int e = 0; e < 8; ++e) {
            float f = bf2f((u16)v[e]);
            c8[e] = (short)f2bf(f + cbias[h * DK + ch * 8 + e]);
            p8[e] = (short)f2bf(f + pbias[h * DK + ch * 8 + e]);
        }
        const int dst = row * 64 + ((ch ^ (row & 7)) * 8);
        *(short8*)&sQc[dst] = c8;
        *(short8*)&sQp[dst] = p8;
    }
    __syncthreads();

    const int arow = w * 16 + (lane & 15);
    short8 aqc[2], aqp[2];
    #pragma unroll
    for (int s = 0; s < 2; ++s) {
        const int off = arow * 64 + (((s * 4 + (lane >> 4)) ^ (arow & 7)) * 8);
        aqc[s] = *(const short8*)&sQc[off];
        aqp[s] = *(const short8*)&sQp[off];
    }

    f32x4 O[12];
    #pragma unroll
    for (int i = 0; i < 12; ++i) O[i] = (f32x4){0.f, 0.f, 0.f, 0.f};
    float M[4] = {-3e38f, -3e38f, -3e38f, -3e38f};
    float L[4] = {0.f, 0.f, 0.f, 0.f};
    const int growb = w * 16 + ((lane >> 4) << 2);

    for (int jt = 0; jt < 24; ++jt) {
        const int j0 = jt * 64;
        for (int t = tid; t < 512; t += 256) {
            const int row = t >> 3, ch = t & 7;
            short8 v = *(const short8*)(kb + ((size_t)(b * N_SEQ + j0 + row)) * QKS
                                           + h * DK + ch * 8);
            *(short8*)&sKP[row * 64 + ((ch ^ (row & 7)) * 8)] = v;
        }
        const int rbase = (N_SEQ - 64) + j0 - i0;
        for (int t = tid; t < 1024; t += 256) {
            const int row = t >> 3, ch = t & 7;
            short8 v = {0, 0, 0, 0, 0, 0, 0, 0};
            if (row < 127)
                v = *(const short8*)(relkb + ((size_t)(rbase + row)) * HDK
                                           + h * DK + ch * 8);
            *(short8*)&sRs[row * 64 + ((ch ^ (row & 7)) * 8)] = v;
        }
        __syncthreads();

        f32x4 S[4], G[8];
        #pragma unroll
        for (int f = 0; f < 4; ++f) S[f] = (f32x4){0.f, 0.f, 0.f, 0.f};
        #pragma unroll
        for (int f = 0; f < 8; ++f) G[f] = (f32x4){0.f, 0.f, 0.f, 0.f};
        #pragma unroll
        for (int s = 0; s < 2; ++s) {
            #pragma unroll
            for (int f = 0; f < 4; ++f) {
                const int br = f * 16 + (lane & 15);
                short8 bb = *(const short8*)&sKP[br * 64 + (((s * 4 + (lane >> 4)) ^ (br & 7)) * 8)];
                S[f] = MFMA_B16(aqc[s], bb, S[f]);
            }
            #pragma unroll
            for (int f = 0; f < 8; ++f) {
                const int br = f * 16 + (lane & 15);
                short8 bb = *(const short8*)&sRs[br * 64 + (((s * 4 + (lane >> 4)) ^ (br & 7)) * 8)];
                G[f] = MFMA_B16(aqp[s], bb, G[f]);
            }
        }
        #pragma unroll
        for (int f = 0; f < 8; ++f)
            #pragma unroll
            for (int r = 0; r < 4; ++r)
                sG[(growb + r) * 134 + f * 16 + (lane & 15)] = G[f][r];
        __syncthreads();

        #pragma unroll
        for (int r = 0; r < 4; ++r) {
            const int ii = growb + r;
            const int gb = ii * 133 + 63;
            float mr = -3e38f;
            #pragma unroll
            for (int f = 0; f < 4; ++f) {
                const float val = S[f][r] + sG[gb + f * 16 + (lane & 15)];
                S[f][r] = val;
                mr = fmaxf(mr, val);
            }
            mr = fmaxf(mr, __shfl_xor(mr, 1, 64));
            mr = fmaxf(mr, __shfl_xor(mr, 2, 64));
            mr = fmaxf(mr, __shfl_xor(mr, 4, 64));
            mr = fmaxf(mr, __shfl_xor(mr, 8, 64));
            const float newM = fmaxf(M[r], mr);
            const float sc = __expf(M[r] - newM);
            M[r] = newM;
            float rs = 0.f;
            #pragma unroll
            for (int f = 0; f < 4; ++f) {
                const float p = __expf(S[f][r] - newM);
                S[f][r] = p;
                rs += p;
            }
            rs += __shfl_xor(rs, 1, 64);
            rs += __shfl_xor(rs, 2, 64);
            rs += __shfl_xor(rs, 4, 64);
            rs += __shfl_xor(rs, 8, 64);
            L[r] = L[r] * sc + rs;
            #pragma unroll
            for (int cf = 0; cf < 12; ++cf) O[cf][r] *= sc;
        }
        #pragma unroll
        for (int f = 0; f < 4; ++f) {
            const int jj = f * 16 + (lane & 15);
            #pragma unroll
            for (int r = 0; r < 4; ++r) {
                const int ii = growb + r;
                sKP[ii * 64 + (((jj >> 3) ^ (ii & 7)) * 8) + (jj & 7)] = f2bf(S[f][r]);
            }
        }
        __syncthreads();
        #pragma unroll
        for (int s = 0; s < 2; ++s) {
            short8 a = *(const short8*)&sKP[arow * 64 + (((s * 4 + (lane >> 4)) ^ (arow & 7)) * 8)];
            const u16* vp = vtb + ((size_t)((b * 8 + h) * DV + (lane & 15))) * N_SEQ
                                + j0 + s * 32 + 8 * (lane >> 4);
            #pragma unroll
            for (int cf = 0; cf < 12; ++cf) {
                short8 bb = *(const short8*)(vp + (size_t)cf * 16 * N_SEQ);
                O[cf] = MFMA_B16(a, bb, O[cf]);
            }
        }
        __syncthreads();
    }
    #pragma unroll
    for (int cf = 0; cf < 12; ++cf) {
        #pragma unroll
        for (int r = 0; r < 4; ++r) {
            const int ii = growb + r;
            att[((size_t)(b * N_SEQ + i0 + ii)) * HDV + h * DV + cf * 16 + (lane & 15)] =
                f2bf(O[cf][r] / L[r]);
        }
    }
}

extern "C" void kernel_launch(void* const* d_in, const int* in_sizes, int n_in,
                              void* d_out, int out_size, void* d_ws, size_t ws_size,
                              hipStream_t stream) {
    const float* x    = (const float*)d_in[0];
    const float* Wq   = (const float*)d_in[1];
    const float* Wk   = (const float*)d_in[2];
    const float* Wv   = (const float*)d_in[3];
    const float* Wrel = (const float*)d_in[4];
    const float* cb   = (const float*)d_in[5];
    const float* pb   = (const float*)d_in[6];
    const float* Wout = (const float*)d_in[7];
    const float* bout = (const float*)d_in[8];
    float* out = (float*)d_out;

    const int M = B_SZ * N_SEQ;                 // 6144
    u16* ws16  = (u16*)d_ws;
    u16* xb    = ws16;                          // 6144x1536 (reused as att later)
    u16* qkb   = xb    + (size_t)M * HDV;       // 6144x1024 (q | k)
    u16* vb    = qkb   + (size_t)M * QKS;       // 6144x1536
    u16* vtb   = vb    + (size_t)M * HDV;       // 32x192x1536
    u16* posb  = vtb   + (size_t)M * HDV;       // 3072x192
    u16* relkb = posb  + (size_t)3072 * NRPF;   // 3072x512
    u16* wqkt  = relkb + (size_t)3072 * HDK;    // 1024x1536
    u16* wvt   = wqkt  + (size_t)QKS * D_MODEL; // 1536x1536
    u16* woutt = wvt   + (size_t)HDV * D_MODEL; // 1536x1536
    u16* wrelt = woutt + (size_t)D_MODEL * HDV; // 512x192
    u16* attb  = xb;                            // alias: xb dead after projections

    dim3 blk(256);
    pos_embed_kernel<<<3072, 96, 0, stream>>>(posb);
    cvt_bf16<<<(M * D_MODEL / 8 + 255) / 256, blk, 0, stream>>>(x, xb, M * D_MODEL / 8);
    transpose_w<<<dim3(HDK / 32, D_MODEL / 32), blk, 0, stream>>>(Wq, wqkt, D_MODEL, HDK, 0.125f);
    transpose_w<<<dim3(HDK / 32, D_MODEL / 32), blk, 0, stream>>>(Wk, wqkt + (size_t)HDK * D_MODEL, D_MODEL, HDK, 1.0f);
    transpose_w<<<dim3(HDV / 32, D_MODEL / 32), blk, 0, stream>>>(Wv, wvt, D_MODEL, HDV, 1.0f);
    transpose_w<<<dim3(D_MODEL / 32, HDV / 32), blk, 0, stream>>>(Wout, woutt, HDV, D_MODEL, 1.0f);
    transpose_w<<<dim3(HDK / 32, NRPF / 32), blk, 0, stream>>>(Wrel, wrelt, NRPF, HDK, 1.0f);

    gemm_bf16<<<dim3(QKS / BN, M / BM), blk, 0, stream>>>(
        xb, wqkt, qkb, nullptr, nullptr, M, QKS, D_MODEL);
    gemm_bf16<<<dim3(HDV / BN, M / BM), blk, 0, stream>>>(
        xb, wvt, vb, nullptr, nullptr, M, HDV, D_MODEL);
    gemm_bf16<<<dim3(HDK / BN, 3072 / BM), blk, 0, stream>>>(
        posb, wrelt, relkb, nullptr, nullptr, NREL, HDK, NRPF);
    transpose_v<<<dim3(N_SEQ / 64, DV / 64, B_SZ * H_N), blk, 0, stream>>>(vb, vtb);
    attn_mfma<<<dim3(N_SEQ / 64, H_N, B_SZ), blk, 0, stream>>>(
        qkb, qkb + HDK, vtb, relkb, cb, pb, attb);
    gemm_bf16<<<dim3(D_MODEL / BN, M / BM), blk, 0, stream>>>(
        attb, woutt, nullptr, out, bout, M, D_MODEL, HDV);
}